// Round 2
// baseline (2939.584 us; speedup 1.0000x reference)
//
#include <hip/hip_runtime.h>
#include <cstdint>
#include <cstddef>

#define HH  128      // H
#define KP1 65       // K+1
#define KD  32       // K_DIFF
#define NB  4096     // B

// thread (trow,tcol) owns rows trow*4..+3, cols {tcol*4..+3, 64+tcol*4..+3}
// (split-column pair -> w_ch read bank start = 4*tcol -> 2-way alias only)

#define FM8(AS, W0, W1, ACCROW) do {                 \
    ACCROW[0] = fmaf(AS, W0.x, ACCROW[0]);           \
    ACCROW[1] = fmaf(AS, W0.y, ACCROW[1]);           \
    ACCROW[2] = fmaf(AS, W0.z, ACCROW[2]);           \
    ACCROW[3] = fmaf(AS, W0.w, ACCROW[3]);           \
    ACCROW[4] = fmaf(AS, W1.x, ACCROW[4]);           \
    ACCROW[5] = fmaf(AS, W1.y, ACCROW[5]);           \
    ACCROW[6] = fmaf(AS, W1.z, ACCROW[6]);           \
    ACCROW[7] = fmaf(AS, W1.w, ACCROW[7]);           \
} while (0)

// ---------------------------------------------------------------------------
// Kernel A: fused gather + 2-layer node MLP.
// rows gr in [0, 2*B*65): side = gr/(B*65); rem = gr%(B*65); k = rem%65
// x(256) = [text[rem,:], emb_tab[ind[rem]][:]]
// nodes[gr] = relu(relu(x@W1+b1)@W2+b2)
// 64x128 tile, 256 threads, 4x8 microtile.
// ---------------------------------------------------------------------------
__global__ __launch_bounds__(256, 2) void node_mlp_kernel(
    const float* __restrict__ user_text, const float* __restrict__ item_text,
    const int*   __restrict__ user_inds, const int*   __restrict__ item_inds,
    const float* __restrict__ user_emb,  const float* __restrict__ item_emb,
    const float* __restrict__ W1, const float* __restrict__ b1v,
    const float* __restrict__ W2, const float* __restrict__ b2v,
    float* __restrict__ nodes)
{
    __shared__ float a_ch[64][36];    // 32-wide K chunk, +4 pad
    __shared__ float w_ch[32][128];
    __shared__ float x1s[64][132];    // stage-1 output, +4 pad

    const int tid  = threadIdx.x;
    const int trow = tid >> 4;
    const int tcol = tid & 15;
    const int c0   = tcol * 4;        // first col quad
    const int c1   = 64 + tcol * 4;   // second col quad
    const int row0 = blockIdx.x * 64;

    // loader: 4 threads per row, 8 floats each (seg 0/8/16/24)
    const int lr  = tid >> 2;
    const int seg = (tid & 3) * 8;
    const int gr_l   = row0 + lr;
    const int side_l = gr_l / (NB * KP1);
    const int rem_l  = gr_l - side_l * (NB * KP1);
    const int k_l    = rem_l % KP1;
    const float* text_row = (side_l ? item_text : user_text) + (size_t)rem_l * HH;
    const int    ind_l    = (side_l ? item_inds : user_inds)[rem_l];
    const float* tab_l    = (side_l == 0) ? ((k_l < KD) ? item_emb : user_emb)
                                          : ((k_l < KD) ? user_emb : item_emb);
    const float* emb_row  = tab_l + (size_t)ind_l * HH;

    const int wr = tid >> 3;          // 0..31
    const int ws = (tid & 7) * 16;    // 0..112

    float acc[4][8];
#pragma unroll
    for (int i = 0; i < 4; ++i)
#pragma unroll
        for (int j = 0; j < 8; ++j) acc[i][j] = 0.f;

    // ---------------- stage 1: K = 256 ----------------
    for (int kc = 0; kc < 2 * HH; kc += 32) {
        const float* asrc = (kc + seg < HH) ? (text_row + kc + seg)
                                            : (emb_row + (kc + seg - HH));
        float4 av0 = *(const float4*)(asrc);
        float4 av1 = *(const float4*)(asrc + 4);
        const float* wsrc = W1 + (size_t)(kc + wr) * HH + ws;
        float4 wv0 = *(const float4*)(wsrc);
        float4 wv1 = *(const float4*)(wsrc + 4);
        float4 wv2 = *(const float4*)(wsrc + 8);
        float4 wv3 = *(const float4*)(wsrc + 12);
        __syncthreads();   // prior compute done reading LDS
        *(float4*)&a_ch[lr][seg]      = av0;
        *(float4*)&a_ch[lr][seg + 4]  = av1;
        *(float4*)&w_ch[wr][ws]       = wv0;
        *(float4*)&w_ch[wr][ws + 4]   = wv1;
        *(float4*)&w_ch[wr][ws + 8]   = wv2;
        *(float4*)&w_ch[wr][ws + 12]  = wv3;
        __syncthreads();
#pragma unroll
        for (int kk4 = 0; kk4 < 8; ++kk4) {
            const int kb = kk4 * 4;
            float4 av[4];
#pragma unroll
            for (int i = 0; i < 4; ++i) av[i] = *(const float4*)&a_ch[trow * 4 + i][kb];
            float4 wA[4], wB[4];
#pragma unroll
            for (int t = 0; t < 4; ++t) {
                wA[t] = *(const float4*)&w_ch[kb + t][c0];
                wB[t] = *(const float4*)&w_ch[kb + t][c1];
            }
#pragma unroll
            for (int i = 0; i < 4; ++i) {
                FM8(av[i].x, wA[0], wB[0], acc[i]);
                FM8(av[i].y, wA[1], wB[1], acc[i]);
                FM8(av[i].z, wA[2], wB[2], acc[i]);
                FM8(av[i].w, wA[3], wB[3], acc[i]);
            }
        }
    }

    // bias + relu -> x1s
    {
        float4 b0 = *(const float4*)(b1v + c0);
        float4 b1 = *(const float4*)(b1v + c1);
        const float bias[8] = {b0.x, b0.y, b0.z, b0.w, b1.x, b1.y, b1.z, b1.w};
#pragma unroll
        for (int i = 0; i < 4; ++i) {
            float tmp[8];
#pragma unroll
            for (int j = 0; j < 8; ++j) {
                tmp[j] = fmaxf(acc[i][j] + bias[j], 0.f);
                acc[i][j] = 0.f;
            }
            *(float4*)&x1s[trow * 4 + i][c0] = *(float4*)&tmp[0];
            *(float4*)&x1s[trow * 4 + i][c1] = *(float4*)&tmp[4];
        }
    }

    // ---------------- stage 2: K = 128 ----------------
    for (int kc = 0; kc < HH; kc += 32) {
        const float* wsrc = W2 + (size_t)(kc + wr) * HH + ws;
        float4 wv0 = *(const float4*)(wsrc);
        float4 wv1 = *(const float4*)(wsrc + 4);
        float4 wv2 = *(const float4*)(wsrc + 8);
        float4 wv3 = *(const float4*)(wsrc + 12);
        __syncthreads();   // x1s visible + prior w_ch reads done
        *(float4*)&w_ch[wr][ws]      = wv0;
        *(float4*)&w_ch[wr][ws + 4]  = wv1;
        *(float4*)&w_ch[wr][ws + 8]  = wv2;
        *(float4*)&w_ch[wr][ws + 12] = wv3;
        __syncthreads();
#pragma unroll
        for (int kk4 = 0; kk4 < 8; ++kk4) {
            const int kb = kk4 * 4;
            float4 av[4];
#pragma unroll
            for (int i = 0; i < 4; ++i) av[i] = *(const float4*)&x1s[trow * 4 + i][kc + kb];
            float4 wA[4], wB[4];
#pragma unroll
            for (int t = 0; t < 4; ++t) {
                wA[t] = *(const float4*)&w_ch[kb + t][c0];
                wB[t] = *(const float4*)&w_ch[kb + t][c1];
            }
#pragma unroll
            for (int i = 0; i < 4; ++i) {
                FM8(av[i].x, wA[0], wB[0], acc[i]);
                FM8(av[i].y, wA[1], wB[1], acc[i]);
                FM8(av[i].z, wA[2], wB[2], acc[i]);
                FM8(av[i].w, wA[3], wB[3], acc[i]);
            }
        }
    }

    {
        float4 b0 = *(const float4*)(b2v + c0);
        float4 b1 = *(const float4*)(b2v + c1);
        const float bias[8] = {b0.x, b0.y, b0.z, b0.w, b1.x, b1.y, b1.z, b1.w};
#pragma unroll
        for (int i = 0; i < 4; ++i) {
            const int gr = row0 + trow * 4 + i;
            float tmp[8];
#pragma unroll
            for (int j = 0; j < 8; ++j) tmp[j] = fmaxf(acc[i][j] + bias[j], 0.f);
            float* dst = nodes + (size_t)gr * HH;
            *(float4*)(dst + c0) = *(float4*)&tmp[0];
            *(float4*)(dst + c1) = *(float4*)&tmp[4];
        }
    }
}

// ---------------------------------------------------------------------------
// Kernel B: attention per (side, b). 8192 blocks, 256 threads.
// ---------------------------------------------------------------------------
__global__ __launch_bounds__(256, 2) void att_kernel(
    const float* __restrict__ nodes,
    const float* __restrict__ user_diff_rel, const float* __restrict__ item_diff_rel,
    const float* __restrict__ A1, const float* __restrict__ ab1,
    const float* __restrict__ A2, const float* __restrict__ ab2,
    float* __restrict__ ufeat)
{
    __shared__ float ne_s[64][132];
    __shared__ float rel_s[32][132];
    __shared__ float w_ch[32][128];
    __shared__ float this_s[128];
    __shared__ float v0[128];
    __shared__ float att_s[64];

    const int tid  = threadIdx.x;
    const int bid  = blockIdx.x;
    const int side = bid >> 12;
    const int b    = bid & (NB - 1);

    const float* nbase = nodes + (size_t)((side * NB + b) * KP1) * HH;
    const float* drel  = (side ? item_diff_rel : user_diff_rel) + (size_t)b * KD * HH;

    if (tid < HH) this_s[tid] = nbase[64 * HH + tid];
    for (int idx = tid; idx < 64 * 32; idx += 256) {       // ne: 64x128 float4
        const int r = idx >> 5, c = (idx & 31) * 4;
        *(float4*)&ne_s[r][c] = *(const float4*)(nbase + r * HH + c);
    }
    for (int idx = tid; idx < 32 * 32; idx += 256) {       // diff_rel: 32x128
        const int r = idx >> 5, c = (idx & 31) * 4;
        *(float4*)&rel_s[r][c] = *(const float4*)(drel + r * HH + c);
    }
    __syncthreads();

    // v0[c] = ab1[c] + sum_d this[d]*A1[d][c]   (rank-1 "this" block)
    if (tid < HH) {
        float s = ab1[tid];
#pragma unroll 8
        for (int d = 0; d < HH; ++d) s = fmaf(this_s[d], A1[(size_t)d * HH + tid], s);
        v0[tid] = s;
    }
    __syncthreads();

    const int trow = tid >> 4;
    const int tcol = tid & 15;
    const int c0   = tcol * 4;
    const int c1   = 64 + tcol * 4;

    float acc[4][8];
    {
        float4 a0 = *(const float4*)&v0[c0];
        float4 a1 = *(const float4*)&v0[c1];
#pragma unroll
        for (int i = 0; i < 4; ++i) {
            acc[i][0] = a0.x; acc[i][1] = a0.y; acc[i][2] = a0.z; acc[i][3] = a0.w;
            acc[i][4] = a1.x; acc[i][5] = a1.y; acc[i][6] = a1.z; acc[i][7] = a1.w;
        }
    }

    const int wr = tid >> 3;
    const int ws = (tid & 7) * 16;

    // part=0 -> rel block (A1 rows 128..255), part=1 -> ne block (rows 256..383)
#pragma unroll
    for (int part = 0; part < 2; ++part) {
        const float* Wbase = A1 + (size_t)(HH + part * HH) * HH;
        for (int kc = 0; kc < HH; kc += 32) {
            const float* wsrc = Wbase + (size_t)(kc + wr) * HH + ws;
            float4 wv0 = *(const float4*)(wsrc);
            float4 wv1 = *(const float4*)(wsrc + 4);
            float4 wv2 = *(const float4*)(wsrc + 8);
            float4 wv3 = *(const float4*)(wsrc + 12);
            __syncthreads();
            *(float4*)&w_ch[wr][ws]      = wv0;
            *(float4*)&w_ch[wr][ws + 4]  = wv1;
            *(float4*)&w_ch[wr][ws + 8]  = wv2;
            *(float4*)&w_ch[wr][ws + 12] = wv3;
            __syncthreads();
#pragma unroll
            for (int kk4 = 0; kk4 < 8; ++kk4) {
                const int kb = kk4 * 4;
                const int d0 = kc + kb;
                float4 av[4];
                if (part == 0) {
                    float4 th4 = *(const float4*)&this_s[d0];
#pragma unroll
                    for (int i = 0; i < 4; ++i) {
                        const int r = trow * 4 + i;
                        if (r < KD) {
                            av[i] = *(const float4*)&rel_s[r][d0];
                        } else {
                            float4 n = *(const float4*)&ne_s[r][d0];
                            av[i].x = n.x * th4.x; av[i].y = n.y * th4.y;
                            av[i].z = n.z * th4.z; av[i].w = n.w * th4.w;
                        }
                    }
                } else {
#pragma unroll
                    for (int i = 0; i < 4; ++i)
                        av[i] = *(const float4*)&ne_s[trow * 4 + i][d0];
                }
                float4 wA[4], wB[4];
#pragma unroll
                for (int t = 0; t < 4; ++t) {
                    wA[t] = *(const float4*)&w_ch[kb + t][c0];
                    wB[t] = *(const float4*)&w_ch[kb + t][c1];
                }
#pragma unroll
                for (int i = 0; i < 4; ++i) {
                    FM8(av[i].x, wA[0], wB[0], acc[i]);
                    FM8(av[i].y, wA[1], wB[1], acc[i]);
                    FM8(av[i].z, wA[2], wB[2], acc[i]);
                    FM8(av[i].w, wA[3], wB[3], acc[i]);
                }
            }
        }
    }

    // h = relu(acc); s[r] = relu(h . A2 + ab2)
    float w2v[8];
    {
        float4 a0 = *(const float4*)(A2 + c0);
        float4 a1 = *(const float4*)(A2 + c1);
        w2v[0] = a0.x; w2v[1] = a0.y; w2v[2] = a0.z; w2v[3] = a0.w;
        w2v[4] = a1.x; w2v[5] = a1.y; w2v[6] = a1.z; w2v[7] = a1.w;
    }
    const float bb2 = ab2[0];
    float p[4];
#pragma unroll
    for (int i = 0; i < 4; ++i) {
        p[i] = 0.f;
#pragma unroll
        for (int j = 0; j < 8; ++j) p[i] = fmaf(fmaxf(acc[i][j], 0.f), w2v[j], p[i]);
    }
#pragma unroll
    for (int m = 1; m < 16; m <<= 1)
#pragma unroll
        for (int i = 0; i < 4; ++i) p[i] += __shfl_xor(p[i], m);
    if (tcol == 0) {
#pragma unroll
        for (int i = 0; i < 4; ++i) att_s[trow * 4 + i] = fmaxf(p[i] + bb2, 0.f);
    }
    __syncthreads();

    // softmax over 64 (one wave)
    if (tid < 64) {
        const float v = att_s[tid];
        float m = v;
#pragma unroll
        for (int off = 1; off < 64; off <<= 1) m = fmaxf(m, __shfl_xor(m, off));
        const float e = expf(v - m);
        float ssum = e;
#pragma unroll
        for (int off = 1; off < 64; off <<= 1) ssum += __shfl_xor(ssum, off);
        att_s[tid] = e / ssum;
    }
    __syncthreads();

    if (tid < HH) {
        float aggv = 0.f;
#pragma unroll
        for (int k = 0; k < 64; ++k) aggv = fmaf(att_s[k], ne_s[k][tid], aggv);
        float* orow = ufeat + (size_t)(side * NB + b) * 256;
        orow[tid]      = this_s[tid];
        orow[HH + tid] = aggv;
    }
}

// ---------------------------------------------------------------------------
// Kernel C: transform. rows = 2*B; in stride 256; two layers.
// ---------------------------------------------------------------------------
__global__ __launch_bounds__(256, 2) void transform_kernel(
    const float* __restrict__ ufeat,
    const float* __restrict__ W1, const float* __restrict__ b1v,
    const float* __restrict__ W2, const float* __restrict__ b2v,
    float* __restrict__ out)
{
    __shared__ float a_ch[64][36];
    __shared__ float w_ch[32][128];
    __shared__ float x1s[64][132];

    const int tid  = threadIdx.x;
    const int trow = tid >> 4;
    const int tcol = tid & 15;
    const int c0   = tcol * 4;
    const int c1   = 64 + tcol * 4;
    const int row0 = blockIdx.x * 64;

    const int lr  = tid >> 2;
    const int seg = (tid & 3) * 8;
    const float* in_row = ufeat + (size_t)(row0 + lr) * 256;

    const int wr = tid >> 3;
    const int ws = (tid & 7) * 16;

    float acc[4][8];
#pragma unroll
    for (int i = 0; i < 4; ++i)
#pragma unroll
        for (int j = 0; j < 8; ++j) acc[i][j] = 0.f;

    for (int kc = 0; kc < 256; kc += 32) {
        float4 av0 = *(const float4*)(in_row + kc + seg);
        float4 av1 = *(const float4*)(in_row + kc + seg + 4);
        const float* wsrc = W1 + (size_t)(kc + wr) * HH + ws;
        float4 wv0 = *(const float4*)(wsrc);
        float4 wv1 = *(const float4*)(wsrc + 4);
        float4 wv2 = *(const float4*)(wsrc + 8);
        float4 wv3 = *(const float4*)(wsrc + 12);
        __syncthreads();
        *(float4*)&a_ch[lr][seg]     = av0;
        *(float4*)&a_ch[lr][seg + 4] = av1;
        *(float4*)&w_ch[wr][ws]      = wv0;
        *(float4*)&w_ch[wr][ws + 4]  = wv1;
        *(float4*)&w_ch[wr][ws + 8]  = wv2;
        *(float4*)&w_ch[wr][ws + 12] = wv3;
        __syncthreads();
#pragma unroll
        for (int kk4 = 0; kk4 < 8; ++kk4) {
            const int kb = kk4 * 4;
            float4 av[4];
#pragma unroll
            for (int i = 0; i < 4; ++i) av[i] = *(const float4*)&a_ch[trow * 4 + i][kb];
            float4 wA[4], wB[4];
#pragma unroll
            for (int t = 0; t < 4; ++t) {
                wA[t] = *(const float4*)&w_ch[kb + t][c0];
                wB[t] = *(const float4*)&w_ch[kb + t][c1];
            }
#pragma unroll
            for (int i = 0; i < 4; ++i) {
                FM8(av[i].x, wA[0], wB[0], acc[i]);
                FM8(av[i].y, wA[1], wB[1], acc[i]);
                FM8(av[i].z, wA[2], wB[2], acc[i]);
                FM8(av[i].w, wA[3], wB[3], acc[i]);
            }
        }
    }

    {
        float4 b0 = *(const float4*)(b1v + c0);
        float4 b1 = *(const float4*)(b1v + c1);
        const float bias[8] = {b0.x, b0.y, b0.z, b0.w, b1.x, b1.y, b1.z, b1.w};
#pragma unroll
        for (int i = 0; i < 4; ++i) {
            float tmp[8];
#pragma unroll
            for (int j = 0; j < 8; ++j) {
                tmp[j] = fmaxf(acc[i][j] + bias[j], 0.f);
                acc[i][j] = 0.f;
            }
            *(float4*)&x1s[trow * 4 + i][c0] = *(float4*)&tmp[0];
            *(float4*)&x1s[trow * 4 + i][c1] = *(float4*)&tmp[4];
        }
    }

    for (int kc = 0; kc < HH; kc += 32) {
        const float* wsrc = W2 + (size_t)(kc + wr) * HH + ws;
        float4 wv0 = *(const float4*)(wsrc);
        float4 wv1 = *(const float4*)(wsrc + 4);
        float4 wv2 = *(const float4*)(wsrc + 8);
        float4 wv3 = *(const float4*)(wsrc + 12);
        __syncthreads();
        *(float4*)&w_ch[wr][ws]      = wv0;
        *(float4*)&w_ch[wr][ws + 4]  = wv1;
        *(float4*)&w_ch[wr][ws + 8]  = wv2;
        *(float4*)&w_ch[wr][ws + 12] = wv3;
        __syncthreads();
#pragma unroll
        for (int kk4 = 0; kk4 < 8; ++kk4) {
            const int kb = kk4 * 4;
            float4 av[4];
#pragma unroll
            for (int i = 0; i < 4; ++i) av[i] = *(const float4*)&x1s[trow * 4 + i][kc + kb];
            float4 wA[4], wB[4];
#pragma unroll
            for (int t = 0; t < 4; ++t) {
                wA[t] = *(const float4*)&w_ch[kb + t][c0];
                wB[t] = *(const float4*)&w_ch[kb + t][c1];
            }
#pragma unroll
            for (int i = 0; i < 4; ++i) {
                FM8(av[i].x, wA[0], wB[0], acc[i]);
                FM8(av[i].y, wA[1], wB[1], acc[i]);
                FM8(av[i].z, wA[2], wB[2], acc[i]);
                FM8(av[i].w, wA[3], wB[3], acc[i]);
            }
        }
    }

    {
        float4 b0 = *(const float4*)(b2v + c0);
        float4 b1 = *(const float4*)(b2v + c1);
        const float bias[8] = {b0.x, b0.y, b0.z, b0.w, b1.x, b1.y, b1.z, b1.w};
#pragma unroll
        for (int i = 0; i < 4; ++i) {
            const int gr = row0 + trow * 4 + i;
            float tmp[8];
#pragma unroll
            for (int j = 0; j < 8; ++j) tmp[j] = fmaxf(acc[i][j] + bias[j], 0.f);
            float* dst = out + (size_t)gr * HH;
            *(float4*)(dst + c0) = *(float4*)&tmp[0];
            *(float4*)(dst + c1) = *(float4*)&tmp[4];
        }
    }
}

// ---------------------------------------------------------------------------
extern "C" void kernel_launch(void* const* d_in, const int* in_sizes, int n_in,
                              void* d_out, int out_size, void* d_ws, size_t ws_size,
                              hipStream_t stream)
{
    (void)in_sizes; (void)n_in; (void)out_size; (void)ws_size;

    const float* user_text     = (const float*)d_in[0];
    const float* item_text     = (const float*)d_in[1];
    const float* user_diff_rel = (const float*)d_in[2];
    const float* item_diff_rel = (const float*)d_in[3];
    const int*   user_inds     = (const int*)d_in[4];
    const int*   item_inds     = (const int*)d_in[5];
    const float* user_emb      = (const float*)d_in[6];
    const float* item_emb      = (const float*)d_in[7];
    const float* ne_W1         = (const float*)d_in[8];
    const float* ne_b1         = (const float*)d_in[9];
    const float* ne_W2         = (const float*)d_in[10];
    const float* ne_b2         = (const float*)d_in[11];
    const float* att_W1        = (const float*)d_in[12];
    const float* att_b1        = (const float*)d_in[13];
    const float* att_W2        = (const float*)d_in[14];
    const float* att_b2        = (const float*)d_in[15];
    const float* tr_W1         = (const float*)d_in[16];
    const float* tr_b1         = (const float*)d_in[17];
    const float* tr_W2         = (const float*)d_in[18];
    const float* tr_b2         = (const float*)d_in[19];

    float* nodes = (float*)d_ws;                                  // 2*B*65*128 f32
    float* ufeat = nodes + (size_t)2 * NB * KP1 * HH;             // 2*B*256 f32
    float* out   = (float*)d_out;                                 // 2*B*128 f32

    const int rowsA = 2 * NB * KP1;   // 532480, divisible by 64
    hipLaunchKernelGGL(node_mlp_kernel, dim3(rowsA / 64), dim3(256), 0, stream,
                       user_text, item_text, user_inds, item_inds,
                       user_emb, item_emb, ne_W1, ne_b1, ne_W2, ne_b2, nodes);

    hipLaunchKernelGGL(att_kernel, dim3(2 * NB), dim3(256), 0, stream,
                       nodes, user_diff_rel, item_diff_rel,
                       att_W1, att_b1, att_W2, att_b2, ufeat);

    hipLaunchKernelGGL(transform_kernel, dim3(2 * NB / 64), dim3(256), 0, stream,
                       ufeat, tr_W1, tr_b1, tr_W2, tr_b2, out);
}